// Round 1
// baseline (2193.637 us; speedup 1.0000x reference)
//
#include <hip/hip_runtime.h>

namespace {

constexpr int kCin = 32;
constexpr int kD = 48;
constexpr int kSliceN = kD * kD * kD;   // 110592
constexpr int kLRow = 50;               // 48 + 2 halo
constexpr int kLPlane = kLRow * 50;     // 2500 floats per plane

// ---------------- stage 1: per-(c,t) partial sums ----------------
__global__ __launch_bounds__(256) void k_stats_partial(const float* __restrict__ x,
                                                       float* __restrict__ part) {
  const int slice = blockIdx.x >> 2;   // 0..63  (= c*2 + t, matches x layout)
  const int p = blockIdx.x & 3;        // 0..3
  const float4* base = reinterpret_cast<const float4*>(x + (size_t)slice * kSliceN);
  const int per = (kSliceN / 4) / 4;   // 6912 float4 per partial
  const int start = p * per;
  float s = 0.f, sq = 0.f;
  for (int i = start + (int)threadIdx.x; i < start + per; i += 256) {
    float4 v = base[i];
    s += (v.x + v.y) + (v.z + v.w);
    sq += (v.x * v.x + v.y * v.y) + (v.z * v.z + v.w * v.w);
  }
  #pragma unroll
  for (int off = 32; off > 0; off >>= 1) {
    s += __shfl_down(s, off);
    sq += __shfl_down(sq, off);
  }
  __shared__ float red[2][4];
  const int wave = threadIdx.x >> 6;
  if ((threadIdx.x & 63) == 0) { red[0][wave] = s; red[1][wave] = sq; }
  __syncthreads();
  if (threadIdx.x == 0) {
    s = (red[0][0] + red[0][1]) + (red[0][2] + red[0][3]);
    sq = (red[1][0] + red[1][1]) + (red[1][2] + red[1][3]);
    part[blockIdx.x * 2 + 0] = s;
    part[blockIdx.x * 2 + 1] = sq;
  }
}

// ---------------- stage 2: finalize mean/rstd ----------------
__global__ void k_stats_final(const float* __restrict__ part, float* __restrict__ stats) {
  const int slice = threadIdx.x;  // 64 threads
  float s = 0.f, sq = 0.f;
  #pragma unroll
  for (int p = 0; p < 4; ++p) {
    s += part[(slice * 4 + p) * 2 + 0];
    sq += part[(slice * 4 + p) * 2 + 1];
  }
  const float inv_n = 1.0f / (float)kSliceN;
  const float mean = s * inv_n;
  const float var = sq * inv_n - mean * mean;  // biased, as torch
  stats[slice * 2 + 0] = mean;
  stats[slice * 2 + 1] = rsqrtf(var + 1e-5f);
}

// ---------------- conv4d with fused norm+relu on the staging load ----------------
// Block = one output d-slice (48x48 positions, both out t) x 4 couts.
// Grid = 48 * 16 = 768 blocks, 256 threads.
__global__ __launch_bounds__(256) void k_conv(const float* __restrict__ x,
                                              const float* __restrict__ wk,
                                              const float* __restrict__ bias,
                                              const float* __restrict__ stats,
                                              float* __restrict__ out) {
  __shared__ float lds_in[6 * kLPlane];       // [tin(2)][s(3)][50][50], zero halo
  __shared__ __align__(16) float lds_w[324];  // [kt(3)][s(3)][khw(9)][co(4)]

  const int d = blockIdx.x >> 4;
  const int co_base = (blockIdx.x & 15) * 4;
  const int tid = threadIdx.x;

  // Zero LDS once; interior gets overwritten each cin, halo stays 0.
  for (int i = tid; i < 6 * kLPlane; i += 256) lds_in[i] = 0.f;

  // 9 output positions per thread (9*256 = 2304 = 48*48)
  int offp[9];
  #pragma unroll
  for (int k = 0; k < 9; ++k) {
    const int pos = tid + k * 256;
    const int hh = pos / 48;
    const int w = pos - hh * 48;
    offp[k] = (hh + 1) * kLRow + (w + 1);
  }

  float acc[9][2][4];
  #pragma unroll
  for (int k = 0; k < 9; ++k)
    #pragma unroll
    for (int t = 0; t < 2; ++t)
      #pragma unroll
      for (int c = 0; c < 4; ++c) acc[k][t][c] = 0.f;

  const bool s0ok = (d - 1) >= 0;
  const bool s2ok = (d + 1) < kD;

  __syncthreads();

  for (int ci = 0; ci < kCin; ++ci) {
    // ---- stage weights: lds_w[((kt*3+s)*9+khw)*4+co] ----
    for (int i = tid; i < 324; i += 256) {
      const int co = i & 3;
      const int r = i >> 2;
      const int khw = r % 9;
      const int r2 = r / 9;
      const int s = r2 % 3;
      const int kt = r2 / 3;
      const int kh = khw / 3;
      const int kw = khw - kh * 3;
      lds_w[i] = wk[(((((co_base + co) * kCin + ci) * 3 + kt) * 3 + s) * 3 + kh) * 3 + kw];
    }
    // ---- stage input planes (norm + relu fused) ----
    const float m0 = stats[(ci * 2 + 0) * 2 + 0];
    const float r0 = stats[(ci * 2 + 0) * 2 + 1];
    const float m1 = stats[(ci * 2 + 1) * 2 + 0];
    const float r1 = stats[(ci * 2 + 1) * 2 + 1];
    for (int i = tid; i < 6 * 2304; i += 256) {
      const int plane = i / 2304;          // tin*3 + s
      const int rr = i - plane * 2304;
      const int row = rr / 48;
      const int col = rr - row * 48;
      const int tin = plane / 3;
      const int s = plane - tin * 3;
      const int din = d + s - 1;
      if (din >= 0 && din < kD) {
        float v = x[(((ci * 2 + tin) * kD + din) * kD + row) * kD + col];
        v = (v - (tin ? m1 : m0)) * (tin ? r1 : r0);
        v = fmaxf(v, 0.f);
        lds_in[plane * kLPlane + (row + 1) * kLRow + (col + 1)] = v;
      }
      // invalid d planes keep stale data but are never read (s skipped below)
    }
    __syncthreads();

    // ---- compute ----
    const float4* w4 = reinterpret_cast<const float4*>(lds_w);
    #pragma unroll
    for (int s = 0; s < 3; ++s) {
      if ((s == 0 && !s0ok) || (s == 2 && !s2ok)) continue;
      #pragma unroll
      for (int tin = 0; tin < 2; ++tin) {
        const int pb = (tin * 3 + s) * kLPlane;
        #pragma unroll
        for (int khw = 0; khw < 9; ++khw) {
          const int kh = khw / 3;
          const int kw = khw - kh * 3;
          // out t=0 uses kt = 1 + tin ; out t=1 uses kt = tin
          const float4 wA = w4[((1 + tin) * 3 + s) * 9 + khw];
          const float4 wB = w4[((0 + tin) * 3 + s) * 9 + khw];
          #pragma unroll
          for (int k = 0; k < 9; ++k) {
            const float v = lds_in[pb + offp[k] + (kh - 1) * kLRow + (kw - 1)];
            acc[k][0][0] = fmaf(v, wA.x, acc[k][0][0]);
            acc[k][0][1] = fmaf(v, wA.y, acc[k][0][1]);
            acc[k][0][2] = fmaf(v, wA.z, acc[k][0][2]);
            acc[k][0][3] = fmaf(v, wA.w, acc[k][0][3]);
            acc[k][1][0] = fmaf(v, wB.x, acc[k][1][0]);
            acc[k][1][1] = fmaf(v, wB.y, acc[k][1][1]);
            acc[k][1][2] = fmaf(v, wB.z, acc[k][1][2]);
            acc[k][1][3] = fmaf(v, wB.w, acc[k][1][3]);
          }
        }
      }
    }
    __syncthreads();  // before next cin overwrites LDS
  }

  // ---- epilogue: bias + store ----
  float b4[4];
  #pragma unroll
  for (int c = 0; c < 4; ++c) b4[c] = bias[co_base + c];
  #pragma unroll
  for (int k = 0; k < 9; ++k) {
    const int pos = tid + k * 256;
    const int hh = pos / 48;
    const int w = pos - hh * 48;
    #pragma unroll
    for (int t = 0; t < 2; ++t)
      #pragma unroll
      for (int c = 0; c < 4; ++c)
        out[((((co_base + c) * 2 + t) * kD + d) * kD + hh) * kD + w] = acc[k][t][c] + b4[c];
  }
}

}  // namespace

extern "C" void kernel_launch(void* const* d_in, const int* in_sizes, int n_in,
                              void* d_out, int out_size, void* d_ws, size_t ws_size,
                              hipStream_t stream) {
  const float* x = (const float*)d_in[0];
  const float* wk = (const float*)d_in[1];
  const float* bias = (const float*)d_in[2];
  float* out = (float*)d_out;
  float* part = (float*)d_ws;       // 512 floats of partial sums
  float* stats = part + 512;        // 128 floats: (mean, rstd) per (c,t)

  k_stats_partial<<<dim3(256), dim3(256), 0, stream>>>(x, part);
  k_stats_final<<<dim3(1), dim3(64), 0, stream>>>(part, stats);
  k_conv<<<dim3(768), dim3(256), 0, stream>>>(x, wk, bias, stats, out);
}

// Round 2
// 203.845 us; speedup vs baseline: 10.7613x; 10.7613x over previous
//
#include <hip/hip_runtime.h>

namespace {

typedef unsigned short u16;
typedef __attribute__((ext_vector_type(8))) short short8;
typedef __attribute__((ext_vector_type(4))) float f32x4;

constexpr int kD = 48;
constexpr int kCin = 32;
constexpr int kSliceN = kD * kD * kD;  // 110592

__device__ inline u16 f2bf(float f) {
  unsigned u = __float_as_uint(f);
  u += 0x7fffu + ((u >> 16) & 1u);   // RNE
  return (u16)(u >> 16);
}

__device__ inline void gl_lds16(const void* g, void* l) {
  __builtin_amdgcn_global_load_lds(
      (const __attribute__((address_space(1))) unsigned int*)g,
      (__attribute__((address_space(3))) unsigned int*)l, 16, 0, 0);
}

// ---------------- stage 1: per-(c,t) partial sums ----------------
__global__ __launch_bounds__(256) void k_stats_partial(const float* __restrict__ x,
                                                       float* __restrict__ part) {
  const int slice = blockIdx.x >> 2;
  const int p = blockIdx.x & 3;
  const float4* base = reinterpret_cast<const float4*>(x + (size_t)slice * kSliceN);
  const int per = (kSliceN / 4) / 4;
  const int start = p * per;
  float s = 0.f, sq = 0.f;
  for (int i = start + (int)threadIdx.x; i < start + per; i += 256) {
    float4 v = base[i];
    s += (v.x + v.y) + (v.z + v.w);
    sq += (v.x * v.x + v.y * v.y) + (v.z * v.z + v.w * v.w);
  }
  #pragma unroll
  for (int off = 32; off > 0; off >>= 1) {
    s += __shfl_down(s, off);
    sq += __shfl_down(sq, off);
  }
  __shared__ float red[2][4];
  const int wave = threadIdx.x >> 6;
  if ((threadIdx.x & 63) == 0) { red[0][wave] = s; red[1][wave] = sq; }
  __syncthreads();
  if (threadIdx.x == 0) {
    s = (red[0][0] + red[0][1]) + (red[0][2] + red[0][3]);
    sq = (red[1][0] + red[1][1]) + (red[1][2] + red[1][3]);
    part[blockIdx.x * 2 + 0] = s;
    part[blockIdx.x * 2 + 1] = sq;
  }
}

// ---------------- stage 2: finalize mean/rstd ----------------
__global__ void k_stats_final(const float* __restrict__ part, float* __restrict__ stats) {
  const int slice = threadIdx.x;  // 64 threads
  float s = 0.f, sq = 0.f;
  #pragma unroll
  for (int p = 0; p < 4; ++p) {
    s += part[(slice * 4 + p) * 2 + 0];
    sq += part[(slice * 4 + p) * 2 + 1];
  }
  const float inv_n = 1.0f / (float)kSliceN;
  const float mean = s * inv_n;
  const float var = sq * inv_n - mean * mean;
  stats[slice * 2 + 0] = mean;
  stats[slice * 2 + 1] = rsqrtf(var + 1e-5f);
}

// ---------------- norm+relu -> channels-last bf16 ----------------
// xn[t][dz][hy][w][ci], one block per (t,dz,hy) row: 48 w x 32 ci.
__global__ __launch_bounds__(256) void k_norm(const float* __restrict__ x,
                                              const float* __restrict__ stats,
                                              u16* __restrict__ xn) {
  __shared__ u16 lt[48 * 32];
  const int tid = threadIdx.x;
  const int bid = blockIdx.x;       // (t*48 + dz)*48 + hy
  const int hy = bid % 48;
  const int td = bid / 48;
  const int t = td / 48;
  const int dz = td % 48;
  for (int i = tid; i < kCin * 48; i += 256) {
    const int ci = i / 48;
    const int w = i - ci * 48;
    const float mean = stats[(ci * 2 + t) * 2 + 0];
    const float rstd = stats[(ci * 2 + t) * 2 + 1];
    float v = x[(((size_t)(ci * 2 + t) * 48 + dz) * 48 + hy) * 48 + w];
    v = fmaxf((v - mean) * rstd, 0.f);
    lt[w * 32 + ci] = f2bf(v);
  }
  __syncthreads();
  const f32x4* src = (const f32x4*)lt;          // 3072 B = 192 x 16B
  f32x4* dst = (f32x4*)(xn + (size_t)bid * 1536);
  if (tid < 192) dst[tid] = src[tid];
}

// ---------------- weight transform: Wk[co][ci][tap] -> wt[tap][co][ci] bf16 ----
__global__ __launch_bounds__(256) void k_wtrans(const float* __restrict__ wk,
                                                u16* __restrict__ wt) {
  const int idx = blockIdx.x * 256 + threadIdx.x;  // < 165888 = 648*256
  const int ci = idx & 31;
  const int co = (idx >> 5) & 63;
  const int tap = idx >> 11;
  wt[idx] = f2bf(wk[(size_t)(co * 32 + ci) * 81 + tap]);
}

// ---------------- MFMA implicit-GEMM conv ----------------
// Block: (to, dz, h0..h0+7) x 64 cout. 8 waves, wave = one h row.
// Wave tile: M = 48 w (3 frags of 16) x N = 64 co (4 frags of 16), K = ci(32) per tap.
__global__ __launch_bounds__(512, 4) void k_conv(const u16* __restrict__ xn,
                                                 const u16* __restrict__ wt,
                                                 const float* __restrict__ bias,
                                                 float* __restrict__ out) {
  __shared__ u16 xs[2 * 10 * 50 * 32];  // [tin][hh][ww][ci], 64000 B, zero halo
  const int tid = threadIdx.x;
  const int wid = tid >> 6;
  const int lane = tid & 63;
  const int r15 = lane & 15;
  const int kc = lane >> 4;  // 0..3

  const int bid = blockIdx.x;
  const int htile = bid % 6;
  const int tmp = bid / 6;
  const int dz = tmp % 48;
  const int to = tmp / 48;
  const int h0 = htile * 8;

  {  // zero LDS once (halo + possibly-unstaged rows rely on this)
    f32x4 z = {0.f, 0.f, 0.f, 0.f};
    f32x4* p = (f32x4*)xs;
    for (int i = tid; i < 4000; i += 512) p[i] = z;
  }
  __syncthreads();

  f32x4 acc[3][4];
  #pragma unroll
  for (int m = 0; m < 3; ++m)
    #pragma unroll
    for (int g = 0; g < 4; ++g) acc[m][g] = (f32x4){0.f, 0.f, 0.f, 0.f};

  for (int dd = 0; dd < 3; ++dd) {
    const int din = dz + dd - 1;
    const bool valid = (din >= 0) && (din < 48);
    if (valid) {
      // stage 20 rows: (tin,hh); each row = 3072 B contiguous -> 3 x gl_lds16
      for (int r = wid; r < 20; r += 8) {
        const int tin = r / 10;
        const int hh = r - tin * 10;
        const int hin = h0 - 1 + hh;
        if (hin < 0 || hin >= 48) continue;  // wave-uniform
        const u16* src = xn + ((size_t)((tin * 48 + din) * 48 + hin)) * 1536 + lane * 8;
        u16* dstb = xs + (tin * 10 + hh) * 1600 + 32;  // ww=1 start
        #pragma unroll
        for (int p = 0; p < 3; ++p) gl_lds16(src + p * 512, dstb + p * 512);
      }
    }
    __syncthreads();  // drains vmcnt (global_load_lds) + lgkm
    if (valid) {
      #pragma unroll
      for (int tin = 0; tin < 2; ++tin) {
        const int kt = tin - to + 1;  // weight kt index
        #pragma unroll
        for (int kh = 0; kh < 3; ++kh) {
          const u16* arow = xs + (tin * 10 + wid + kh) * 1600;
          #pragma unroll
          for (int kw = 0; kw < 3; ++kw) {
            const int tap = ((kt * 3 + dd) * 3 + kh) * 3 + kw;
            const u16* wb = wt + tap * 2048 + r15 * 32 + kc * 8;
            const short8 b0 = *(const short8*)(wb);
            const short8 b1 = *(const short8*)(wb + 512);
            const short8 b2 = *(const short8*)(wb + 1024);
            const short8 b3 = *(const short8*)(wb + 1536);
            const u16* ab = arow + (r15 + kw) * 32 + kc * 8;
            const short8 a0 = *(const short8*)(ab);
            const short8 a1 = *(const short8*)(ab + 512);
            const short8 a2 = *(const short8*)(ab + 1024);
            acc[0][0] = __builtin_amdgcn_mfma_f32_16x16x32_bf16(a0, b0, acc[0][0], 0, 0, 0);
            acc[0][1] = __builtin_amdgcn_mfma_f32_16x16x32_bf16(a0, b1, acc[0][1], 0, 0, 0);
            acc[0][2] = __builtin_amdgcn_mfma_f32_16x16x32_bf16(a0, b2, acc[0][2], 0, 0, 0);
            acc[0][3] = __builtin_amdgcn_mfma_f32_16x16x32_bf16(a0, b3, acc[0][3], 0, 0, 0);
            acc[1][0] = __builtin_amdgcn_mfma_f32_16x16x32_bf16(a1, b0, acc[1][0], 0, 0, 0);
            acc[1][1] = __builtin_amdgcn_mfma_f32_16x16x32_bf16(a1, b1, acc[1][1], 0, 0, 0);
            acc[1][2] = __builtin_amdgcn_mfma_f32_16x16x32_bf16(a1, b2, acc[1][2], 0, 0, 0);
            acc[1][3] = __builtin_amdgcn_mfma_f32_16x16x32_bf16(a1, b3, acc[1][3], 0, 0, 0);
            acc[2][0] = __builtin_amdgcn_mfma_f32_16x16x32_bf16(a2, b0, acc[2][0], 0, 0, 0);
            acc[2][1] = __builtin_amdgcn_mfma_f32_16x16x32_bf16(a2, b1, acc[2][1], 0, 0, 0);
            acc[2][2] = __builtin_amdgcn_mfma_f32_16x16x32_bf16(a2, b2, acc[2][2], 0, 0, 0);
            acc[2][3] = __builtin_amdgcn_mfma_f32_16x16x32_bf16(a2, b3, acc[2][3], 0, 0, 0);
          }
        }
      }
    }
    __syncthreads();  // protect xs before next slab's staging
  }

  // epilogue: C row = w = m*16 + kc*4 + j, col = co = g*16 + r15
  const int hy = h0 + wid;
  float* ob = out + (size_t)to * 110592 + dz * 2304 + hy * 48;
  #pragma unroll
  for (int g = 0; g < 4; ++g) {
    const int co = g * 16 + r15;
    const float bv = bias[co];
    float* oc = ob + (size_t)co * 221184;
    #pragma unroll
    for (int m = 0; m < 3; ++m) {
      #pragma unroll
      for (int j = 0; j < 4; ++j) oc[m * 16 + kc * 4 + j] = acc[m][g][j] + bv;
    }
  }
}

}  // namespace

extern "C" void kernel_launch(void* const* d_in, const int* in_sizes, int n_in,
                              void* d_out, int out_size, void* d_ws, size_t ws_size,
                              hipStream_t stream) {
  const float* x = (const float*)d_in[0];
  const float* wk = (const float*)d_in[1];
  const float* bias = (const float*)d_in[2];
  float* out = (float*)d_out;

  float* part = (float*)d_ws;                          // 512 f
  float* stats = part + 512;                           // 128 f
  u16* xn = (u16*)((char*)d_ws + 4096);                // 2*48^3*32 u16 = 14155776 B
  u16* wt = xn + 7077888;                              // 165888 u16 = 331776 B

  k_stats_partial<<<dim3(256), dim3(256), 0, stream>>>(x, part);
  k_stats_final<<<dim3(1), dim3(64), 0, stream>>>(part, stats);
  k_wtrans<<<dim3(648), dim3(256), 0, stream>>>(wk, wt);
  k_norm<<<dim3(4608), dim3(256), 0, stream>>>(x, stats, xn);
  k_conv<<<dim3(576), dim3(512), 0, stream>>>(xn, wt, bias, out);
}

// Round 3
// 172.083 us; speedup vs baseline: 12.7475x; 1.1846x over previous
//
#include <hip/hip_runtime.h>

namespace {

typedef unsigned short u16;
typedef __attribute__((ext_vector_type(8))) short short8;
typedef __attribute__((ext_vector_type(4))) float f32x4;
typedef __attribute__((ext_vector_type(4))) unsigned int u32x4;

constexpr int kD = 48;
constexpr int kCin = 32;
constexpr int kSliceN = kD * kD * kD;  // 110592

// DPP convention (per LLVM AMDGPUAtomicOptimizer scan): row_shr:N -> out[n]=in[n-N]
constexpr int SHR1 = 0x111;   // out[n] = in[n-1]  (data moves to higher lanes)
constexpr int SHL1 = 0x101;   // out[n] = in[n+1]
constexpr int SHL15 = 0x10F;  // out[n] = in[n+15] (lane0 <- lane15)
constexpr int SHR15 = 0x11F;  // out[n] = in[n-15] (lane15 <- lane0)

__device__ inline u16 f2bf(float f) {
  unsigned u = __float_as_uint(f);
  u += 0x7fffu + ((u >> 16) & 1u);  // RNE
  return (u16)(u >> 16);
}

__device__ inline void gl_lds16(const void* g, void* l) {
  __builtin_amdgcn_global_load_lds(
      (const __attribute__((address_space(1))) unsigned int*)g,
      (__attribute__((address_space(3))) unsigned int*)l, 16, 0, 0);
}

template <int CM>
__device__ inline short8 dpp4(short8 m) {
  u32x4 mu = __builtin_bit_cast(u32x4, m), r;
  #pragma unroll
  for (int j = 0; j < 4; ++j)
    r[j] = (unsigned)__builtin_amdgcn_update_dpp(0, (int)mu[j], CM, 0xf, 0xf, true);
  return __builtin_bit_cast(short8, r);
}
template <int CM, int CP>
__device__ inline short8 dpp4p(short8 m, short8 nb, bool pl) {
  u32x4 mu = __builtin_bit_cast(u32x4, m), nu = __builtin_bit_cast(u32x4, nb), r;
  #pragma unroll
  for (int j = 0; j < 4; ++j) {
    unsigned a = (unsigned)__builtin_amdgcn_update_dpp(0, (int)mu[j], CM, 0xf, 0xf, true);
    unsigned b = (unsigned)__builtin_amdgcn_update_dpp(0, (int)nu[j], CP, 0xf, 0xf, true);
    r[j] = pl ? b : a;
  }
  return __builtin_bit_cast(short8, r);
}

#define MFMA16(A, B, C) __builtin_amdgcn_mfma_f32_16x16x32_bf16((A), (B), (C), 0, 0, 0)

// ---------------- stage 1: per-(c,t) partial sums ----------------
__global__ __launch_bounds__(256) void k_stats_partial(const float* __restrict__ x,
                                                       float* __restrict__ part) {
  const int slice = blockIdx.x >> 2;
  const int p = blockIdx.x & 3;
  const float4* base = reinterpret_cast<const float4*>(x + (size_t)slice * kSliceN);
  const int per = (kSliceN / 4) / 4;
  const int start = p * per;
  float s = 0.f, sq = 0.f;
  for (int i = start + (int)threadIdx.x; i < start + per; i += 256) {
    float4 v = base[i];
    s += (v.x + v.y) + (v.z + v.w);
    sq += (v.x * v.x + v.y * v.y) + (v.z * v.z + v.w * v.w);
  }
  #pragma unroll
  for (int off = 32; off > 0; off >>= 1) {
    s += __shfl_down(s, off);
    sq += __shfl_down(sq, off);
  }
  __shared__ float red[2][4];
  const int wave = threadIdx.x >> 6;
  if ((threadIdx.x & 63) == 0) { red[0][wave] = s; red[1][wave] = sq; }
  __syncthreads();
  if (threadIdx.x == 0) {
    s = (red[0][0] + red[0][1]) + (red[0][2] + red[0][3]);
    sq = (red[1][0] + red[1][1]) + (red[1][2] + red[1][3]);
    part[blockIdx.x * 2 + 0] = s;
    part[blockIdx.x * 2 + 1] = sq;
  }
}

// ---------------- stage 2: finalize mean/rstd ----------------
__global__ void k_stats_final(const float* __restrict__ part, float* __restrict__ stats) {
  const int slice = threadIdx.x;  // 64 threads
  float s = 0.f, sq = 0.f;
  #pragma unroll
  for (int p = 0; p < 4; ++p) {
    s += part[(slice * 4 + p) * 2 + 0];
    sq += part[(slice * 4 + p) * 2 + 1];
  }
  const float inv_n = 1.0f / (float)kSliceN;
  const float mean = s * inv_n;
  const float var = sq * inv_n - mean * mean;
  stats[slice * 2 + 0] = mean;
  stats[slice * 2 + 1] = rsqrtf(var + 1e-5f);
}

// ---------------- norm+relu -> channels-last bf16, bank-swizzled rows ----------------
// xn row (t,dz,hy) = 48w x 32ci = 192 granules of 16B, granule (w,kcg):
//   gdst = (w>>2)*16 + ((kcg ^ ((w>>2)&3))<<2) + (w&3)
__global__ __launch_bounds__(256) void k_norm(const float* __restrict__ x,
                                              const float* __restrict__ stats,
                                              u16* __restrict__ xn) {
  __shared__ u16 lt[48 * 32];
  const int tid = threadIdx.x;
  const int bid = blockIdx.x;  // (t*48 + dz)*48 + hy
  const int hy = bid % 48;
  const int td = bid / 48;
  const int t = td / 48;
  const int dz = td % 48;
  for (int i = tid; i < kCin * 48; i += 256) {
    const int ci = i / 48;
    const int w = i - ci * 48;
    const float mean = stats[(ci * 2 + t) * 2 + 0];
    const float rstd = stats[(ci * 2 + t) * 2 + 1];
    float v = x[(((size_t)(ci * 2 + t) * 48 + dz) * 48 + hy) * 48 + w];
    v = fmaxf((v - mean) * rstd, 0.f);
    lt[w * 32 + ci] = f2bf(v);
  }
  __syncthreads();
  if (tid < 192) {
    const int w = tid >> 2, kcg = tid & 3, q = w >> 2;
    const int gd = q * 16 + ((kcg ^ (q & 3)) << 2) + (w & 3);
    ((f32x4*)(xn + (size_t)bid * 1536))[gd] = ((const f32x4*)lt)[tid];
  }
}

// ---------------- weight transform: Wk[co][ci][tap] -> wt[tap][co][ci] bf16 ----
__global__ __launch_bounds__(256) void k_wtrans(const float* __restrict__ wk,
                                                u16* __restrict__ wt) {
  const int idx = blockIdx.x * 256 + threadIdx.x;  // < 165888
  const int ci = idx & 31;
  const int co = (idx >> 5) & 63;
  const int tap = idx >> 11;
  wt[idx] = f2bf(wk[(size_t)(co * 32 + ci) * 81 + tap]);
}

// ---------------- MFMA implicit-GEMM conv, DPP kw-shifts ----------------
// Block: 256 thr (4 waves) = (to, dz, 8 h-rows) x 64 co. Wave: 2 rows (Mf=6), Nf=4.
// C = W x X (swapped operands): C row = co, col = w -> coalesced stores.
__global__ __launch_bounds__(256, 2) void k_conv(const u16* __restrict__ xn,
                                                 const u16* __restrict__ wt,
                                                 const float* __restrict__ bias,
                                                 float* __restrict__ out) {
  __shared__ u16 xs[2 * 10 * 48 * 32];  // 61440 B, rows swizzled like xn
  const int tid = threadIdx.x, wid = tid >> 6, lane = tid & 63;
  const int r15 = lane & 15, kc = lane >> 4;
  const int bid = blockIdx.x;
  const int ht = bid % 6;
  const int dz = (bid / 6) % 48;
  const int to = bid / 288;
  const int h0 = ht * 8;

  {  // zero LDS once (h-edge rows stay zero; they are never re-staged)
    f32x4 z = {0.f, 0.f, 0.f, 0.f};
    f32x4* p = (f32x4*)xs;
    for (int i = tid; i < 3840; i += 256) p[i] = z;
  }

  int grano[3];
  #pragma unroll
  for (int wf = 0; wf < 3; ++wf) {
    const int w = wf * 16 + r15, q = w >> 2;
    grano[wf] = (q * 16 + ((kc ^ (q & 3)) << 2) + (w & 3)) << 4;  // byte offset in row
  }
  const bool pl0 = (r15 == 0), pl15 = (r15 == 15);

  f32x4 acc[4][2][3];
  #pragma unroll
  for (int g = 0; g < 4; ++g)
    #pragma unroll
    for (int rr = 0; rr < 2; ++rr)
      #pragma unroll
      for (int wf = 0; wf < 3; ++wf) acc[g][rr][wf] = (f32x4){0.f, 0.f, 0.f, 0.f};

  __syncthreads();

  for (int dd = 0; dd < 3; ++dd) {
    const int din = dz + dd - 1;
    const bool vd = (din >= 0) && (din < 48);
    if (vd) {
      for (int u = wid; u < 20; u += 4) {  // wave-uniform unit
        const int tin = u / 10, hh = u - tin * 10, hin = h0 - 1 + hh;
        if (hin < 0 || hin >= 48) continue;
        const u16* src = xn + ((size_t)((tin * 48 + din) * 48 + hin)) * 1536 + lane * 8;
        u16* dstb = xs + u * 1536;
        #pragma unroll
        for (int p = 0; p < 3; ++p) gl_lds16(src + p * 512, dstb + p * 512);
      }
    }
    __syncthreads();  // drain gl_lds
    if (vd) {
      #pragma unroll
      for (int tin = 0; tin < 2; ++tin) {
        const int kt = tin + 1 - to;
        short8 xr[4][3];  // rows 2wid..2wid+3 of this tin, aligned wfrags
        #pragma unroll
        for (int ri = 0; ri < 4; ++ri) {
          const u16* rb = xs + (tin * 10 + 2 * wid + ri) * 1536;
          #pragma unroll
          for (int wf = 0; wf < 3; ++wf)
            xr[ri][wf] = *(const short8*)((const char*)rb + grano[wf]);
        }
        #pragma unroll
        for (int kh = 0; kh < 3; ++kh) {
          const int tapb = ((kt * 3 + dd) * 3 + kh) * 3;
          short8 wB[3][4];
          #pragma unroll
          for (int kw = 0; kw < 3; ++kw) {
            const u16* wb = wt + (size_t)(tapb + kw) * 2048 + r15 * 32 + kc * 8;
            #pragma unroll
            for (int g = 0; g < 4; ++g) wB[kw][g] = *(const short8*)(wb + g * 512);
          }
          #pragma unroll
          for (int rr = 0; rr < 2; ++rr) {
            const short8 aC0 = xr[kh + rr][0], aC1 = xr[kh + rr][1], aC2 = xr[kh + rr][2];
            // x at w-1 (kw=0): shift data to higher lanes; lane0 patched from prev frag lane15
            const short8 aL0 = dpp4<SHR1>(aC0);                  // lane0 -> 0 == x[-1] pad
            const short8 aL1 = dpp4p<SHR1, SHL15>(aC1, aC0, pl0);
            const short8 aL2 = dpp4p<SHR1, SHL15>(aC2, aC1, pl0);
            // x at w+1 (kw=2)
            const short8 aR0 = dpp4p<SHL1, SHR15>(aC0, aC1, pl15);
            const short8 aR1 = dpp4p<SHL1, SHR15>(aC1, aC2, pl15);
            const short8 aR2 = dpp4<SHL1>(aC2);                  // lane15 -> 0 == x[48] pad
            #pragma unroll
            for (int g = 0; g < 4; ++g) {
              acc[g][rr][0] = MFMA16(wB[0][g], aL0, acc[g][rr][0]);
              acc[g][rr][0] = MFMA16(wB[1][g], aC0, acc[g][rr][0]);
              acc[g][rr][0] = MFMA16(wB[2][g], aR0, acc[g][rr][0]);
              acc[g][rr][1] = MFMA16(wB[0][g], aL1, acc[g][rr][1]);
              acc[g][rr][1] = MFMA16(wB[1][g], aC1, acc[g][rr][1]);
              acc[g][rr][1] = MFMA16(wB[2][g], aR1, acc[g][rr][1]);
              acc[g][rr][2] = MFMA16(wB[0][g], aL2, acc[g][rr][2]);
              acc[g][rr][2] = MFMA16(wB[1][g], aC2, acc[g][rr][2]);
              acc[g][rr][2] = MFMA16(wB[2][g], aR2, acc[g][rr][2]);
            }
          }
        }
      }
    }
    __syncthreads();  // protect xs before next slab staging
  }

  // epilogue: C row = co = g*16 + kc*4 + j, col = w = wf*16 + r15 (coalesced over lanes)
  float bv[4][4];
  #pragma unroll
  for (int g = 0; g < 4; ++g)
    #pragma unroll
    for (int j = 0; j < 4; ++j) bv[g][j] = bias[g * 16 + kc * 4 + j];
  const int hyb = h0 + 2 * wid;
  #pragma unroll
  for (int g = 0; g < 4; ++g) {
    #pragma unroll
    for (int rr = 0; rr < 2; ++rr) {
      const int hy = hyb + rr;
      float* ob = out + (size_t)to * 110592 + (size_t)dz * 2304 + (size_t)hy * 48;
      #pragma unroll
      for (int wf = 0; wf < 3; ++wf) {
        const int w = wf * 16 + r15;
        #pragma unroll
        for (int j = 0; j < 4; ++j) {
          const int co = g * 16 + kc * 4 + j;
          ob[(size_t)co * 221184 + w] = acc[g][rr][wf][j] + bv[g][j];
        }
      }
    }
  }
}

}  // namespace

extern "C" void kernel_launch(void* const* d_in, const int* in_sizes, int n_in,
                              void* d_out, int out_size, void* d_ws, size_t ws_size,
                              hipStream_t stream) {
  const float* x = (const float*)d_in[0];
  const float* wk = (const float*)d_in[1];
  const float* bias = (const float*)d_in[2];
  float* out = (float*)d_out;

  float* part = (float*)d_ws;            // 512 f
  float* stats = part + 512;             // 128 f
  u16* xn = (u16*)((char*)d_ws + 4096);  // 2*48^3*32 u16 = 14155776 B (swizzled rows)
  u16* wt = xn + 7077888;                // 165888 u16

  k_stats_partial<<<dim3(256), dim3(256), 0, stream>>>(x, part);
  k_stats_final<<<dim3(1), dim3(64), 0, stream>>>(part, stats);
  k_wtrans<<<dim3(648), dim3(256), 0, stream>>>(wk, wt);
  k_norm<<<dim3(4608), dim3(256), 0, stream>>>(x, stats, xn);
  k_conv<<<dim3(576), dim3(256), 0, stream>>>(xn, wt, bias, out);
}

// Round 6
// 150.505 us; speedup vs baseline: 14.5752x; 1.1434x over previous
//
#include <hip/hip_runtime.h>

namespace {

typedef unsigned short u16;
typedef __attribute__((ext_vector_type(8))) short short8;
typedef __attribute__((ext_vector_type(4))) float f32x4;
typedef __attribute__((ext_vector_type(4))) unsigned int u32x4;

constexpr int kD = 48;
constexpr int kSliceN = kD * kD * kD;  // 110592
constexpr int kP = 8;                  // partials per (c,t) slice

// DPP convention: row_shr:N -> out[n]=in[n-N]
constexpr int SHR1 = 0x111;   // out[n] = in[n-1]
constexpr int SHL1 = 0x101;   // out[n] = in[n+1]
constexpr int SHL15 = 0x10F;  // lane0 <- lane15
constexpr int SHR15 = 0x11F;  // lane15 <- lane0

__device__ inline u16 f2bf(float f) {
  unsigned u = __float_as_uint(f);
  u += 0x7fffu + ((u >> 16) & 1u);  // RNE
  return (u16)(u >> 16);
}

__device__ inline void gl_lds16(const void* g, void* l) {
  __builtin_amdgcn_global_load_lds(
      (const __attribute__((address_space(1))) unsigned int*)g,
      (__attribute__((address_space(3))) unsigned int*)l, 16, 0, 0);
}

template <int CM>
__device__ inline short8 dpp4(short8 m) {
  u32x4 mu = __builtin_bit_cast(u32x4, m), r;
  #pragma unroll
  for (int j = 0; j < 4; ++j)
    r[j] = (unsigned)__builtin_amdgcn_update_dpp(0, (int)mu[j], CM, 0xf, 0xf, true);
  return __builtin_bit_cast(short8, r);
}
template <int CM, int CP>
__device__ inline short8 dpp4p(short8 m, short8 nb, bool pl) {
  u32x4 mu = __builtin_bit_cast(u32x4, m), nu = __builtin_bit_cast(u32x4, nb), r;
  #pragma unroll
  for (int j = 0; j < 4; ++j) {
    unsigned a = (unsigned)__builtin_amdgcn_update_dpp(0, (int)mu[j], CM, 0xf, 0xf, true);
    unsigned b = (unsigned)__builtin_amdgcn_update_dpp(0, (int)nu[j], CP, 0xf, 0xf, true);
    r[j] = pl ? b : a;
  }
  return __builtin_bit_cast(short8, r);
}

#define MFMA16(A, B, C) __builtin_amdgcn_mfma_f32_16x16x32_bf16((A), (B), (C), 0, 0, 0)

// ---------------- stats partials: 512 blocks = 64 slices x 8 ----------------
__global__ __launch_bounds__(256) void k_stats_partial(const float* __restrict__ x,
                                                       float* __restrict__ part) {
  const int slice = blockIdx.x >> 3;
  const int p = blockIdx.x & 7;
  const float4* base = reinterpret_cast<const float4*>(x + (size_t)slice * kSliceN);
  const int per = (kSliceN / 4) / kP;  // 3456
  const int start = p * per;
  float s = 0.f, sq = 0.f;
  for (int i = start + (int)threadIdx.x; i < start + per; i += 256) {
    float4 v = base[i];
    s += (v.x + v.y) + (v.z + v.w);
    sq += (v.x * v.x + v.y * v.y) + (v.z * v.z + v.w * v.w);
  }
  #pragma unroll
  for (int off = 32; off > 0; off >>= 1) {
    s += __shfl_down(s, off);
    sq += __shfl_down(sq, off);
  }
  __shared__ float red[2][4];
  const int wave = threadIdx.x >> 6;
  if ((threadIdx.x & 63) == 0) { red[0][wave] = s; red[1][wave] = sq; }
  __syncthreads();
  if (threadIdx.x == 0) {
    s = (red[0][0] + red[0][1]) + (red[0][2] + red[0][3]);
    sq = (red[1][0] + red[1][1]) + (red[1][2] + red[1][3]);
    part[blockIdx.x * 2 + 0] = s;
    part[blockIdx.x * 2 + 1] = sq;
  }
}

// ---------------- weight transform: 64 blocks (one per co) ----------------
// wk[co][ci][tap] fp32 -> wt[tap][co][ci] bf16
__global__ __launch_bounds__(256) void k_wtrans(const float* __restrict__ wk,
                                                u16* __restrict__ wt) {
  __shared__ float lw[2592];  // [ci(32)][tap(81)]
  const int co = blockIdx.x;
  const int tid = threadIdx.x;
  const float4* src = reinterpret_cast<const float4*>(wk + (size_t)co * 2592);
  #pragma unroll
  for (int k = 0; k < 3; ++k) {
    const int i = tid + k * 256;
    if (i < 648) ((float4*)lw)[i] = src[i];
  }
  __syncthreads();
  for (int g = tid; g < 324; g += 256) {  // tap(81) x kcg(4)
    const int tap = g >> 2, kcg = g & 3;
    u32x4 o;
    #pragma unroll
    for (int j = 0; j < 4; ++j) {
      const unsigned lo = f2bf(lw[(kcg * 8 + 2 * j + 0) * 81 + tap]);
      const unsigned hi = f2bf(lw[(kcg * 8 + 2 * j + 1) * 81 + tap]);
      o[j] = lo | (hi << 16);
    }
    *(u32x4*)(wt + (size_t)tap * 2048 + co * 32 + kcg * 8) = o;
  }
}

// ---------------- norm+relu -> channels-last bf16, swizzled granule rows ----------
// 768 blocks = (t, dz, hs 0..7), 6 hy rows each. Stats-final fused in.
// xn row (t,dz,hy): granule (w,kcg) at gd = q*16 + ((kcg^(q&3))<<2) + (w&3), q=w>>2.
__global__ __launch_bounds__(256) void k_norm(const float* __restrict__ x,
                                              const float* __restrict__ part,
                                              u16* __restrict__ xn) {
  __shared__ u16 ls[6 * 1536];  // [hy][ci][w] : hy*1536 + ci*48 + w
  __shared__ float sm[32], sr[32];
  const int tid = threadIdx.x;
  const int bid = blockIdx.x;
  const int hs = bid & 7;
  const int dz = (bid >> 3) % 48;
  const int t = bid / 384;
  const int hy0 = hs * 6;

  if (tid < 32) {
    const int slice = tid * 2 + t;
    float s = 0.f, sq = 0.f;
    #pragma unroll
    for (int p = 0; p < kP; ++p) {
      s += part[(slice * kP + p) * 2 + 0];
      sq += part[(slice * kP + p) * 2 + 1];
    }
    const float inv_n = 1.0f / (float)kSliceN;
    const float mean = s * inv_n;
    const float var = sq * inv_n - mean * mean;
    sm[tid] = mean;
    sr[tid] = rsqrtf(var + 1e-5f);
  }
  __syncthreads();

  // stage 1: 2304 float4 coalesced loads, normalize+relu, bf16 -> LDS
  #pragma unroll
  for (int k = 0; k < 9; ++k) {
    const int F = tid + k * 256;       // ci*72 + hy*12 + wc
    const int ci = F / 72;
    const int rem = F - ci * 72;
    const int hy = rem / 12;
    const int wc = rem - hy * 12;
    const float4 v = *reinterpret_cast<const float4*>(
        x + (size_t)(ci * 2 + t) * 110592 + dz * 2304 + (hy0 + hy) * 48 + wc * 4);
    const float mean = sm[ci], rstd = sr[ci];
    const unsigned a0 = f2bf(fmaxf((v.x - mean) * rstd, 0.f));
    const unsigned a1 = f2bf(fmaxf((v.y - mean) * rstd, 0.f));
    const unsigned a2 = f2bf(fmaxf((v.z - mean) * rstd, 0.f));
    const unsigned a3 = f2bf(fmaxf((v.w - mean) * rstd, 0.f));
    uint2 pk;
    pk.x = a0 | (a1 << 16);
    pk.y = a2 | (a3 << 16);
    *reinterpret_cast<uint2*>(ls + hy * 1536 + ci * 48 + wc * 4) = pk;
  }
  __syncthreads();

  // stage 2: gather granules (8 ci for fixed w), pack, coalesced swizzled store
  const size_t rb = ((size_t)(t * 48 + dz) * 48 + hy0) * 1536;
  #pragma unroll
  for (int k = 0; k < 5; ++k) {
    const int g = tid + k * 256;  // hy*192 + kcg*48 + w
    if (g >= 1152) break;
    const int hy = g / 192;
    const int rem = g - hy * 192;
    const int kcg = rem / 48;
    const int w = rem - kcg * 48;
    const u16* base = ls + hy * 1536 + w;
    u32x4 o;
    #pragma unroll
    for (int j = 0; j < 4; ++j) {
      const unsigned lo = base[(kcg * 8 + 2 * j + 0) * 48];
      const unsigned hi = base[(kcg * 8 + 2 * j + 1) * 48];
      o[j] = lo | (hi << 16);
    }
    const int q = w >> 2;
    const int gd = q * 16 + ((kcg ^ (q & 3)) << 2) + (w & 3);
    *(u32x4*)(xn + rb + (size_t)hy * 1536 + gd * 8) = o;
  }
}

// ---------------- MFMA implicit-GEMM conv: wave = co-16 group x all M ----------
// Block: 256 thr (4 waves) = (to, dz, 4 h-rows) x 64 co. Wave wid owns co group
// wid*16..wid*16+15 and computes all 12 M-frags (4 rows x 3 wfrags).
// Grid 1152 = 2 to x 12 ht x 48 dz, bijective XCD swizzle (1152 = 8*144).
__global__ __launch_bounds__(256, 4) void k_conv(const u16* __restrict__ xn,
                                                 const u16* __restrict__ wt,
                                                 const float* __restrict__ bias,
                                                 float* __restrict__ out) {
  __shared__ u16 xs[12 * 1536];  // [tin(2)][hh(6)] rows, 36864 B, single buffer
  const int tid = threadIdx.x, wid = tid >> 6, lane = tid & 63;
  const int r15 = lane & 15, kc = lane >> 4;

  const int orig = blockIdx.x;
  const int swz = (orig & 7) * 144 + (orig >> 3);  // bijective on [0,1152)
  const int to = swz & 1;
  const int ht = (swz >> 1) % 12;
  const int dz = swz / 24;  // 0..47
  const int h0 = ht * 4;

  {  // zero full buffer once (h-edge rows rely on staying zero; dd-invariant skip set)
    f32x4 z = {0.f, 0.f, 0.f, 0.f};
    f32x4* p = (f32x4*)xs;
    #pragma unroll
    for (int k = 0; k < 9; ++k) p[tid + k * 256] = z;  // 2304 = full 36864 B
  }

  int grano[3];
  #pragma unroll
  for (int wf = 0; wf < 3; ++wf) {
    const int w = wf * 16 + r15, q = w >> 2;
    grano[wf] = (q * 16 + ((kc ^ (q & 3)) << 2) + (w & 3)) << 4;  // byte offset
  }
  const bool pl0 = (r15 == 0), pl15 = (r15 == 15);

  f32x4 acc[4][3];  // [m_row][wf]
  #pragma unroll
  for (int m = 0; m < 4; ++m)
    #pragma unroll
    for (int wf = 0; wf < 3; ++wf) acc[m][wf] = (f32x4){0.f, 0.f, 0.f, 0.f};

  __syncthreads();  // zero-init visible before first staging

  for (int dd = 0; dd < 3; ++dd) {
    const int din = dz + dd - 1;
    const bool vd = (din >= 0) && (din < 48);
    if (vd) {
      for (int u = wid; u < 12; u += 4) {  // 3 rows per wave, wave-uniform
        const int tin = u / 6, hh = u - tin * 6;
        const int hin = h0 - 1 + hh;
        if (hin < 0 || hin >= 48) continue;  // wave-uniform skip (stays zero)
        const u16* src = xn + ((size_t)((tin * 48 + din) * 48 + hin)) * 1536 + lane * 8;
        u16* dstb = xs + u * 1536;
        #pragma unroll
        for (int p = 0; p < 3; ++p) gl_lds16(src + p * 512, dstb + p * 512);
      }
    }
    __syncthreads();  // staged data visible (drains gl_lds)
    if (vd) {
      #pragma unroll
      for (int tin = 0; tin < 2; ++tin) {
        const int kt = tin + 1 - to;
        #pragma unroll
        for (int half = 0; half < 2; ++half) {
          // window: lds rows tin*6 + 2*half + 0..3 ; m_rows 2*half + {0,1}
          short8 xr[4][3];
          #pragma unroll
          for (int ri = 0; ri < 4; ++ri) {
            const char* rb = (const char*)(xs + (tin * 6 + 2 * half + ri) * 1536);
            #pragma unroll
            for (int wf = 0; wf < 3; ++wf)
              xr[ri][wf] = *(const short8*)(rb + grano[wf]);
          }
          #pragma unroll
          for (int kh = 0; kh < 3; ++kh) {
            const int tapb = ((kt * 3 + dd) * 3 + kh) * 3;
            short8 wB[3];
            #pragma unroll
            for (int kw = 0; kw < 3; ++kw)
              wB[kw] = *(const short8*)(wt + (size_t)(tapb + kw) * 2048 + wid * 512 +
                                        r15 * 32 + kc * 8);
            #pragma unroll
            for (int mr = 0; mr < 2; ++mr) {
              const int m = 2 * half + mr;
              const short8 aC0 = xr[mr + kh][0], aC1 = xr[mr + kh][1], aC2 = xr[mr + kh][2];
              const short8 aL0 = dpp4<SHR1>(aC0);
              const short8 aL1 = dpp4p<SHR1, SHL15>(aC1, aC0, pl0);
              const short8 aL2 = dpp4p<SHR1, SHL15>(aC2, aC1, pl0);
              const short8 aR0 = dpp4p<SHL1, SHR15>(aC0, aC1, pl15);
              const short8 aR1 = dpp4p<SHL1, SHR15>(aC1, aC2, pl15);
              const short8 aR2 = dpp4<SHL1>(aC2);
              acc[m][0] = MFMA16(wB[0], aL0, acc[m][0]);
              acc[m][0] = MFMA16(wB[1], aC0, acc[m][0]);
              acc[m][0] = MFMA16(wB[2], aR0, acc[m][0]);
              acc[m][1] = MFMA16(wB[0], aL1, acc[m][1]);
              acc[m][1] = MFMA16(wB[1], aC1, acc[m][1]);
              acc[m][1] = MFMA16(wB[2], aR1, acc[m][1]);
              acc[m][2] = MFMA16(wB[0], aL2, acc[m][2]);
              acc[m][2] = MFMA16(wB[1], aC2, acc[m][2]);
              acc[m][2] = MFMA16(wB[2], aR2, acc[m][2]);
            }
          }
        }
      }
    }
    __syncthreads();  // compute done before next slab overwrites xs
  }

  // epilogue: C row = co = wid*16 + kc*4 + j, col = w = wf*16 + r15
  float bv[4];
  #pragma unroll
  for (int j = 0; j < 4; ++j) bv[j] = bias[wid * 16 + kc * 4 + j];
  #pragma unroll
  for (int m = 0; m < 4; ++m) {
    const int hy = h0 + m;
    float* ob = out + (size_t)to * 110592 + (size_t)dz * 2304 + (size_t)hy * 48;
    #pragma unroll
    for (int wf = 0; wf < 3; ++wf) {
      const int w = wf * 16 + r15;
      #pragma unroll
      for (int j = 0; j < 4; ++j) {
        const int co = wid * 16 + kc * 4 + j;
        ob[(size_t)co * 221184 + w] = acc[m][wf][j] + bv[j];
      }
    }
  }
}

}  // namespace

extern "C" void kernel_launch(void* const* d_in, const int* in_sizes, int n_in,
                              void* d_out, int out_size, void* d_ws, size_t ws_size,
                              hipStream_t stream) {
  const float* x = (const float*)d_in[0];
  const float* wk = (const float*)d_in[1];
  const float* bias = (const float*)d_in[2];
  float* out = (float*)d_out;

  float* part = (float*)d_ws;            // 1024 f32 = 4096 B
  u16* xn = (u16*)((char*)d_ws + 4096);  // 2*48^3*32 u16 = 14155776 B (swizzled rows)
  u16* wt = xn + 7077888;                // 165888 u16

  k_stats_partial<<<dim3(512), dim3(256), 0, stream>>>(x, part);
  k_wtrans<<<dim3(64), dim3(256), 0, stream>>>(wk, wt);
  k_norm<<<dim3(768), dim3(256), 0, stream>>>(x, part, xn);
  k_conv<<<dim3(1152), dim3(256), 0, stream>>>(xn, wt, bias, out);
}

// Round 7
// 139.510 us; speedup vs baseline: 15.7239x; 1.0788x over previous
//
#include <hip/hip_runtime.h>

namespace {

typedef unsigned short u16;
typedef __attribute__((ext_vector_type(8))) short short8;
typedef __attribute__((ext_vector_type(4))) float f32x4;
typedef __attribute__((ext_vector_type(4))) unsigned int u32x4;

constexpr int kD = 48;
constexpr int kSliceN = kD * kD * kD;  // 110592
constexpr int kP = 8;                  // partials per (c,t) slice

// DPP convention: row_shr:N -> out[n]=in[n-N]
constexpr int SHR1 = 0x111;   // out[n] = in[n-1]
constexpr int SHL1 = 0x101;   // out[n] = in[n+1]
constexpr int SHL15 = 0x10F;  // lane0 <- lane15
constexpr int SHR15 = 0x11F;  // lane15 <- lane0

__device__ inline u16 f2bf(float f) {
  unsigned u = __float_as_uint(f);
  u += 0x7fffu + ((u >> 16) & 1u);  // RNE
  return (u16)(u >> 16);
}

__device__ inline void gl_lds16(const void* g, void* l) {
  __builtin_amdgcn_global_load_lds(
      (const __attribute__((address_space(1))) unsigned int*)g,
      (__attribute__((address_space(3))) unsigned int*)l, 16, 0, 0);
}

template <int CM>
__device__ inline short8 dpp4(short8 m) {
  u32x4 mu = __builtin_bit_cast(u32x4, m), r;
  #pragma unroll
  for (int j = 0; j < 4; ++j)
    r[j] = (unsigned)__builtin_amdgcn_update_dpp(0, (int)mu[j], CM, 0xf, 0xf, true);
  return __builtin_bit_cast(short8, r);
}
template <int CM, int CP>
__device__ inline short8 dpp4p(short8 m, short8 nb, bool pl) {
  u32x4 mu = __builtin_bit_cast(u32x4, m), nu = __builtin_bit_cast(u32x4, nb), r;
  #pragma unroll
  for (int j = 0; j < 4; ++j) {
    unsigned a = (unsigned)__builtin_amdgcn_update_dpp(0, (int)mu[j], CM, 0xf, 0xf, true);
    unsigned b = (unsigned)__builtin_amdgcn_update_dpp(0, (int)nu[j], CP, 0xf, 0xf, true);
    r[j] = pl ? b : a;
  }
  return __builtin_bit_cast(short8, r);
}

#define MFMA16(A, B, C) __builtin_amdgcn_mfma_f32_16x16x32_bf16((A), (B), (C), 0, 0, 0)

// ------- fused prep: blocks 0..63 = wtrans (co), 64..575 = stats partials -------
// wk[co][ci][tap] fp32 -> wt[tap][co][ci] bf16 ; stats: 512 blocks = 64 slices x 8
__global__ __launch_bounds__(256) void k_prep(const float* __restrict__ x,
                                              const float* __restrict__ wk,
                                              float* __restrict__ part,
                                              u16* __restrict__ wt) {
  const int tid = threadIdx.x;
  if (blockIdx.x < 64) {
    __shared__ float lw[2592];  // [ci(32)][tap(81)]
    const int co = blockIdx.x;
    const float4* src = reinterpret_cast<const float4*>(wk + (size_t)co * 2592);
    #pragma unroll
    for (int k = 0; k < 3; ++k) {
      const int i = tid + k * 256;
      if (i < 648) ((float4*)lw)[i] = src[i];
    }
    __syncthreads();
    for (int g = tid; g < 324; g += 256) {  // tap(81) x kcg(4)
      const int tap = g >> 2, kcg = g & 3;
      u32x4 o;
      #pragma unroll
      for (int j = 0; j < 4; ++j) {
        const unsigned lo = f2bf(lw[(kcg * 8 + 2 * j + 0) * 81 + tap]);
        const unsigned hi = f2bf(lw[(kcg * 8 + 2 * j + 1) * 81 + tap]);
        o[j] = lo | (hi << 16);
      }
      *(u32x4*)(wt + (size_t)tap * 2048 + co * 32 + kcg * 8) = o;
    }
    return;
  }
  const int sbid = blockIdx.x - 64;
  const int slice = sbid >> 3;
  const int p = sbid & 7;
  const float4* base = reinterpret_cast<const float4*>(x + (size_t)slice * kSliceN);
  const int per = (kSliceN / 4) / kP;  // 3456
  const int start = p * per;
  float s = 0.f, sq = 0.f;
  for (int i = start + tid; i < start + per; i += 256) {
    float4 v = base[i];
    s += (v.x + v.y) + (v.z + v.w);
    sq += (v.x * v.x + v.y * v.y) + (v.z * v.z + v.w * v.w);
  }
  #pragma unroll
  for (int off = 32; off > 0; off >>= 1) {
    s += __shfl_down(s, off);
    sq += __shfl_down(sq, off);
  }
  __shared__ float red[2][4];
  const int wave = tid >> 6;
  if ((tid & 63) == 0) { red[0][wave] = s; red[1][wave] = sq; }
  __syncthreads();
  if (tid == 0) {
    s = (red[0][0] + red[0][1]) + (red[0][2] + red[0][3]);
    sq = (red[1][0] + red[1][1]) + (red[1][2] + red[1][3]);
    part[sbid * 2 + 0] = s;
    part[sbid * 2 + 1] = sq;
  }
}

// ---------------- norm+relu -> channels-last bf16, swizzled granule rows ----------
// 768 blocks = (t, dz, hs 0..7), 6 hy rows each. Stats-final fused in.
// xn row (t,dz,hy): granule (w,kcg) at gd = q*16 + ((kcg^(q&3))<<2) + (w&3), q=w>>2.
__global__ __launch_bounds__(256) void k_norm(const float* __restrict__ x,
                                              const float* __restrict__ part,
                                              u16* __restrict__ xn) {
  __shared__ u16 ls[6 * 1536];  // [hy][ci][w] : hy*1536 + ci*48 + w
  __shared__ float sm[32], sr[32];
  const int tid = threadIdx.x;
  const int bid = blockIdx.x;
  const int hs = bid & 7;
  const int dz = (bid >> 3) % 48;
  const int t = bid / 384;
  const int hy0 = hs * 6;

  if (tid < 32) {
    const int slice = tid * 2 + t;
    float s = 0.f, sq = 0.f;
    #pragma unroll
    for (int p = 0; p < kP; ++p) {
      s += part[(slice * kP + p) * 2 + 0];
      sq += part[(slice * kP + p) * 2 + 1];
    }
    const float inv_n = 1.0f / (float)kSliceN;
    const float mean = s * inv_n;
    const float var = sq * inv_n - mean * mean;
    sm[tid] = mean;
    sr[tid] = rsqrtf(var + 1e-5f);
  }
  __syncthreads();

  // stage 1: 2304 float4 coalesced loads, normalize+relu, bf16 -> LDS
  #pragma unroll
  for (int k = 0; k < 9; ++k) {
    const int F = tid + k * 256;       // ci*72 + hy*12 + wc
    const int ci = F / 72;
    const int rem = F - ci * 72;
    const int hy = rem / 12;
    const int wc = rem - hy * 12;
    const float4 v = *reinterpret_cast<const float4*>(
        x + (size_t)(ci * 2 + t) * 110592 + dz * 2304 + (hy0 + hy) * 48 + wc * 4);
    const float mean = sm[ci], rstd = sr[ci];
    const unsigned a0 = f2bf(fmaxf((v.x - mean) * rstd, 0.f));
    const unsigned a1 = f2bf(fmaxf((v.y - mean) * rstd, 0.f));
    const unsigned a2 = f2bf(fmaxf((v.z - mean) * rstd, 0.f));
    const unsigned a3 = f2bf(fmaxf((v.w - mean) * rstd, 0.f));
    uint2 pk;
    pk.x = a0 | (a1 << 16);
    pk.y = a2 | (a3 << 16);
    *reinterpret_cast<uint2*>(ls + hy * 1536 + ci * 48 + wc * 4) = pk;
  }
  __syncthreads();

  // stage 2: gather granules (8 ci for fixed w), pack, coalesced swizzled store
  const size_t rb = ((size_t)(t * 48 + dz) * 48 + hy0) * 1536;
  #pragma unroll
  for (int k = 0; k < 5; ++k) {
    const int g = tid + k * 256;  // hy*192 + kcg*48 + w
    if (g >= 1152) break;
    const int hy = g / 192;
    const int rem = g - hy * 192;
    const int kcg = rem / 48;
    const int w = rem - kcg * 48;
    const u16* base = ls + hy * 1536 + w;
    u32x4 o;
    #pragma unroll
    for (int j = 0; j < 4; ++j) {
      const unsigned lo = base[(kcg * 8 + 2 * j + 0) * 48];
      const unsigned hi = base[(kcg * 8 + 2 * j + 1) * 48];
      o[j] = lo | (hi << 16);
    }
    const int q = w >> 2;
    const int gd = q * 16 + ((kcg ^ (q & 3)) << 2) + (w & 3);
    *(u32x4*)(xn + rb + (size_t)hy * 1536 + gd * 8) = o;
  }
}

// ---------------- MFMA implicit-GEMM conv: per-input-row hoisted DPP ----------
// Block: 256 thr (4 waves) = (to, dz, 6 h-rows) x 64 co. Wave wid owns co group
// wid*16..+15, computes all 18 M-frags (6 rows x 3 wfrags). Input rows are
// DPP-shifted ONCE and applied to all (m = r - kh) consumers.
// Grid 768 = 2 to x 8 ht x 48 dz = exactly 3 blocks/CU; bijective XCD swizzle.
__global__ __launch_bounds__(256, 3) void k_conv(const u16* __restrict__ xn,
                                                 const u16* __restrict__ wt,
                                                 const float* __restrict__ bias,
                                                 float* __restrict__ out) {
  __shared__ u16 xs[16 * 1536];  // [tin(2)][r(8)] rows (48w x 32ci swizzled), 49152 B
  const int tid = threadIdx.x, wid = tid >> 6, lane = tid & 63;
  const int r15 = lane & 15, kc = lane >> 4;

  const int orig = blockIdx.x;
  const int swz = (orig & 7) * 96 + (orig >> 3);  // bijective on [0,768)
  const int to = swz & 1;
  const int ht = (swz >> 1) & 7;
  const int dz = swz >> 4;  // 0..47
  const int h0 = ht * 6;

  {  // zero full buffer once (h-edge rows rely on staying zero; skip set dd-invariant)
    f32x4 z = {0.f, 0.f, 0.f, 0.f};
    f32x4* p = (f32x4*)xs;
    #pragma unroll
    for (int k = 0; k < 12; ++k) p[tid + k * 256] = z;  // 3072 = full 49152 B
  }

  int grano[3];
  #pragma unroll
  for (int wf = 0; wf < 3; ++wf) {
    const int w = wf * 16 + r15, q = w >> 2;
    grano[wf] = (q * 16 + ((kc ^ (q & 3)) << 2) + (w & 3)) << 4;  // byte offset
  }
  const bool pl0 = (r15 == 0), pl15 = (r15 == 15);

  f32x4 acc[6][3];  // [m_row][wf]
  #pragma unroll
  for (int m = 0; m < 6; ++m)
    #pragma unroll
    for (int wf = 0; wf < 3; ++wf) acc[m][wf] = (f32x4){0.f, 0.f, 0.f, 0.f};

  __syncthreads();  // zero-init visible before first staging

  for (int dd = 0; dd < 3; ++dd) {
    const int din = dz + dd - 1;
    const bool vd = (din >= 0) && (din < 48);
    if (vd) {
      for (int u = wid; u < 16; u += 4) {  // 4 rows per wave, wave-uniform
        const int tin = u >> 3, rr = u & 7;
        const int hin = h0 - 1 + rr;
        if (hin < 0 || hin >= 48) continue;  // wave-uniform skip (row stays zero)
        const u16* src = xn + ((size_t)((tin * 48 + din) * 48 + hin)) * 1536 + lane * 8;
        u16* dstb = xs + u * 1536;
        #pragma unroll
        for (int p = 0; p < 3; ++p) gl_lds16(src + p * 512, dstb + p * 512);
      }
    }
    __syncthreads();  // staged data visible (drains gl_lds)
    if (vd) {
      #pragma unroll
      for (int tin = 0; tin < 2; ++tin) {
        const int kt = tin + 1 - to;
        short8 wB[3][3];  // [kh][kw], hoisted for this (kt,dd)
        #pragma unroll
        for (int kh = 0; kh < 3; ++kh)
          #pragma unroll
          for (int kw = 0; kw < 3; ++kw)
            wB[kh][kw] = *(const short8*)(wt +
                (size_t)(((kt * 3 + dd) * 3 + kh) * 3 + kw) * 2048 +
                wid * 512 + r15 * 32 + kc * 8);
        #pragma unroll
        for (int r = 0; r < 8; ++r) {  // input rows; shift once, use for all m=r-kh
          const char* rb = (const char*)(xs + (tin * 8 + r) * 1536);
          const short8 aC0 = *(const short8*)(rb + grano[0]);
          const short8 aC1 = *(const short8*)(rb + grano[1]);
          const short8 aC2 = *(const short8*)(rb + grano[2]);
          const short8 aL0 = dpp4<SHR1>(aC0);
          const short8 aL1 = dpp4p<SHR1, SHL15>(aC1, aC0, pl0);
          const short8 aL2 = dpp4p<SHR1, SHL15>(aC2, aC1, pl0);
          const short8 aR0 = dpp4p<SHL1, SHR15>(aC0, aC1, pl15);
          const short8 aR1 = dpp4p<SHL1, SHR15>(aC1, aC2, pl15);
          const short8 aR2 = dpp4<SHL1>(aC2);
          #pragma unroll
          for (int kh = 0; kh < 3; ++kh) {
            const int m = r - kh;
            if (m < 0 || m > 5) continue;  // compile-time (r,kh unrolled)
            acc[m][0] = MFMA16(wB[kh][0], aL0, acc[m][0]);
            acc[m][0] = MFMA16(wB[kh][1], aC0, acc[m][0]);
            acc[m][0] = MFMA16(wB[kh][2], aR0, acc[m][0]);
            acc[m][1] = MFMA16(wB[kh][0], aL1, acc[m][1]);
            acc[m][1] = MFMA16(wB[kh][1], aC1, acc[m][1]);
            acc[m][1] = MFMA16(wB[kh][2], aR1, acc[m][1]);
            acc[m][2] = MFMA16(wB[kh][0], aL2, acc[m][2]);
            acc[m][2] = MFMA16(wB[kh][1], aC2, acc[m][2]);
            acc[m][2] = MFMA16(wB[kh][2], aR2, acc[m][2]);
          }
        }
      }
    }
    __syncthreads();  // compute done before next slab overwrites xs
  }

  // epilogue: C row = co = wid*16 + kc*4 + j, col = w = wf*16 + r15
  float bv[4];
  #pragma unroll
  for (int j = 0; j < 4; ++j) bv[j] = bias[wid * 16 + kc * 4 + j];
  #pragma unroll
  for (int m = 0; m < 6; ++m) {
    const int hy = h0 + m;
    float* ob = out + (size_t)to * 110592 + (size_t)dz * 2304 + (size_t)hy * 48;
    #pragma unroll
    for (int wf = 0; wf < 3; ++wf) {
      const int w = wf * 16 + r15;
      #pragma unroll
      for (int j = 0; j < 4; ++j) {
        const int co = wid * 16 + kc * 4 + j;
        ob[(size_t)co * 221184 + w] = acc[m][wf][j] + bv[j];
      }
    }
  }
}

}  // namespace

extern "C" void kernel_launch(void* const* d_in, const int* in_sizes, int n_in,
                              void* d_out, int out_size, void* d_ws, size_t ws_size,
                              hipStream_t stream) {
  const float* x = (const float*)d_in[0];
  const float* wk = (const float*)d_in[1];
  const float* bias = (const float*)d_in[2];
  float* out = (float*)d_out;

  float* part = (float*)d_ws;            // 1024 f32 = 4096 B
  u16* xn = (u16*)((char*)d_ws + 4096);  // 2*48^3*32 u16 = 14155776 B (swizzled rows)
  u16* wt = xn + 7077888;                // 165888 u16

  k_prep<<<dim3(576), dim3(256), 0, stream>>>(x, wk, part, wt);
  k_norm<<<dim3(768), dim3(256), 0, stream>>>(x, part, xn);
  k_conv<<<dim3(768), dim3(256), 0, stream>>>(xn, wt, bias, out);
}